// Round 4
// baseline (518.901 us; speedup 1.0000x reference)
//
#include <hip/hip_runtime.h>

#define CCH 384
#define HH 192
#define WWD 192
#define NIMG 2
#define HWP (HH * WWD)        // 36864 pixels per image
#define PTOT (NIMG * HWP)     // 73728
#define HEADS 12
#define HD 32
#define NWIN 24
#define WINS 576              // windows per image
#define EELEM ((size_t)NIMG * CCH * HWP)   // elems per tensor (28,311,552)
#define WMAT 147456           // 384*384

typedef __attribute__((ext_vector_type(8))) short bh8;            // 8 bf16 (MFMA frag)
typedef __attribute__((ext_vector_type(8))) unsigned short us8;
typedef __attribute__((ext_vector_type(4))) unsigned short us4;
typedef __attribute__((ext_vector_type(4))) float fx4;

__device__ __forceinline__ unsigned short f2bf(float f) {
    unsigned u = __float_as_uint(f);
    u += 0x7fffu + ((u >> 16) & 1u);      // round-to-nearest-even
    return (unsigned short)(u >> 16);
}

// ---------------------------------------------------------------------------
// weights fp32 -> bf16 (qp_w, kp_w, vp_w, proj_w concatenated)
// ---------------------------------------------------------------------------
__global__ __launch_bounds__(256) void wcvt(
    const float* __restrict__ a, const float* __restrict__ b,
    const float* __restrict__ c, const float* __restrict__ d,
    unsigned short* __restrict__ o)
{
    int idx8 = (blockIdx.x * 256 + threadIdx.x) * 8;   // 288 blocks * 256 * 8 = 589824 exact
    int which = idx8 / WMAT;
    int loc = idx8 - which * WMAT;
    const float* s = (which == 0) ? a : (which == 1) ? b : (which == 2) ? c : d;
    float4 v0 = *(const float4*)(s + loc);
    float4 v1 = *(const float4*)(s + loc + 4);
    us8 ov;
    ov[0] = f2bf(v0.x); ov[1] = f2bf(v0.y); ov[2] = f2bf(v0.z); ov[3] = f2bf(v0.w);
    ov[4] = f2bf(v1.x); ov[5] = f2bf(v1.y); ov[6] = f2bf(v1.z); ov[7] = f2bf(v1.w);
    *(us8*)(o + idx8) = ov;
}

// ---------------------------------------------------------------------------
// FUSED depthwise 3x3 + bias + window-gather transpose (v2).
// Block = 4 horizontal windows (8 rows x 32 cols) x 96 channels (6 chunks of 16).
// grid = 288 tiles x 4 channel-groups = 1152 blocks, XCD-chunked swizzle.
// LDS halo per chunk: [16 ch][10 rows][40 cols] f32 = 25.6 KB -> 6 blocks/CU.
// Thread = one pixel x 16 channels (channel idx block-uniform -> scalar weights).
// Output: bf16 [p_wg][384] via 16B us8 stores.
// ---------------------------------------------------------------------------
__global__ __launch_bounds__(256) void dwgather(
    const float* __restrict__ x,
    const float* __restrict__ qw, const float* __restrict__ qb,
    const float* __restrict__ kw, const float* __restrict__ kb,
    const float* __restrict__ vw, const float* __restrict__ vb,
    unsigned short* __restrict__ oq, unsigned short* __restrict__ ok,
    unsigned short* __restrict__ ov)
{
    __shared__ float halo[16 * 10 * 40];    // 25.6 KB

    // XCD-chunked bijective swizzle: 1152 blocks, 144 per XCD
    int bid = blockIdx.x;
    int b = (bid & 7) * 144 + (bid >> 3);
    int cgroup = b & 3;
    int tile = b >> 2;                      // 0..287
    int n = tile / 144;
    int trem = tile - n * 144;              // wy*6 + wtx
    int wy = trem / 6, wtx = trem - wy * 6;

    int tid = threadIdx.x;
    int r8 = tid >> 5;                      // 0..7  (row in window)
    int c32 = tid & 31;                     // 0..31 (col in 4-window strip)
    int wloc = c32 >> 3;
    int pxw = r8 * 8 + (c32 & 7);
    int widx = n * WINS + wy * NWIN + wtx * 4 + wloc;
    size_t outbase = ((size_t)widx * 64 + pxw) * CCH;

    const float* xn = x + (size_t)n * CCH * HWP;
    int h0 = wy * 8;                        // staged rows h0-1 .. h0+8
    int col0 = wtx * 32 - 4;                // staged cols col0 .. col0+39

    for (int ch = 0; ch < 6; ++ch) {
        int cg0 = cgroup * 96 + ch * 16;

        __syncthreads();                    // prev chunk's readers done
        for (int job = tid; job < 1600; job += 256) {
            int seg = job % 10;
            int rr  = (job / 10) % 10;
            int cc  = job / 100;
            int hr  = h0 - 1 + rr;
            int cb  = col0 + seg * 4;
            float4 val = make_float4(0.f, 0.f, 0.f, 0.f);
            if (hr >= 0 && hr < HH && cb >= 0 && cb < WWD)
                val = *(const float4*)(xn + (size_t)(cg0 + cc) * HWP
                                          + (size_t)hr * WWD + cb);
            *(float4*)&halo[(cc * 10 + rr) * 40 + seg * 4] = val;
        }
        __syncthreads();

        us8 oqv[2], okv[2], ovv[2];
#pragma unroll
        for (int j = 0; j < 16; ++j) {
            int cg = cg0 + j;
            float sq = 0.f, sk = 0.f, sv = 0.f;
#pragma unroll
            for (int dr = 0; dr < 3; ++dr) {
#pragma unroll
                for (int dc = 0; dc < 3; ++dc) {
                    float xv = halo[(j * 10 + r8 + dr) * 40 + c32 + dc + 3];
                    int t = dr * 3 + dc;
                    sq = fmaf(xv, qw[cg * 9 + t], sq);
                    sk = fmaf(xv, kw[cg * 9 + t], sk);
                    sv = fmaf(xv, vw[cg * 9 + t], sv);
                }
            }
            oqv[j >> 3][j & 7] = f2bf(sq + qb[cg]);
            okv[j >> 3][j & 7] = f2bf(sk + kb[cg]);
            ovv[j >> 3][j & 7] = f2bf(sv + vb[cg]);
        }
        *(us8*)(oq + outbase + cg0)     = oqv[0];
        *(us8*)(oq + outbase + cg0 + 8) = oqv[1];
        *(us8*)(ok + outbase + cg0)     = okv[0];
        *(us8*)(ok + outbase + cg0 + 8) = okv[1];
        *(us8*)(ov + outbase + cg0)     = ovv[0];
        *(us8*)(ov + outbase + cg0 + 8) = ovv[1];
    }
}

// ---------------------------------------------------------------------------
// bf16 MFMA GEMM over channels. Y: bf16 [p_wg][384] (k contiguous).
// W: bf16 [c_out][384]. 128x128 tile, BK=32, 4 waves, 4x4 16x16 frags/wave.
// ORIENT 1: D[c][p] -> out bf16 [p][c], (acc+bias)*scale      (q, k)
// ORIENT 2: D[p][c] -> out bf16 [n][c][p_local], acc+bias     (v, transposed for attn)
// ORIENT 3: D[p][c] -> out fp32 standard [n][c][h][w], un-gather windows (proj)
// ---------------------------------------------------------------------------
template<int ORIENT>
__global__ __launch_bounds__(256) void pw_gemm(
    const unsigned short* __restrict__ Y, const unsigned short* __restrict__ Wb,
    const float* __restrict__ bias, float scale,
    unsigned short* __restrict__ outb, float* __restrict__ outf)
{
    __shared__ unsigned short Wt[128][40];   // [c_out rows][k], padded
    __shared__ unsigned short Yt[128][40];   // [p rows][k], padded

    int tid = threadIdx.x;
    int pp0 = blockIdx.x * 128;
    int cm0 = blockIdx.y * 128;
    int lid = tid & 63, wid = tid >> 6;
    int wr = wid >> 1, wc = wid & 1;
    int li = lid & 15, g = lid >> 4;
    int srow = tid >> 2;                 // 0..63
    int skoff = (tid & 3) * 8;           // 0,8,16,24

    fx4 acc[4][4];
#pragma unroll
    for (int i = 0; i < 4; ++i)
#pragma unroll
        for (int j = 0; j < 4; ++j) acc[i][j] = (fx4){0.f, 0.f, 0.f, 0.f};

    const unsigned short* WpG = Wb + (size_t)(cm0 + srow) * CCH + skoff;
    const unsigned short* YpG = Y  + (size_t)(pp0 + srow) * CCH + skoff;
    bh8 w0 = *(const bh8*)(WpG);
    bh8 w1 = *(const bh8*)(WpG + (size_t)64 * CCH);
    bh8 y0 = *(const bh8*)(YpG);
    bh8 y1 = *(const bh8*)(YpG + (size_t)64 * CCH);

    typedef unsigned short (*tile_t)[40];
    tile_t Asrc = (ORIENT == 1) ? Wt : Yt;
    tile_t Bsrc = (ORIENT == 1) ? Yt : Wt;

    for (int kt = 0; kt < 12; ++kt) {
        __syncthreads();
        *(bh8*)&Wt[srow][skoff]      = w0;
        *(bh8*)&Wt[64 + srow][skoff] = w1;
        *(bh8*)&Yt[srow][skoff]      = y0;
        *(bh8*)&Yt[64 + srow][skoff] = y1;
        __syncthreads();
        if (kt < 11) {
            int ko = (kt + 1) * 32;
            w0 = *(const bh8*)(WpG + ko);
            w1 = *(const bh8*)(WpG + ko + (size_t)64 * CCH);
            y0 = *(const bh8*)(YpG + ko);
            y1 = *(const bh8*)(YpG + ko + (size_t)64 * CCH);
        }
        bh8 a[4], b[4];
#pragma unroll
        for (int mf = 0; mf < 4; ++mf)
            a[mf] = *(const bh8*)&Asrc[wr * 64 + mf * 16 + li][g * 8];
#pragma unroll
        for (int nf = 0; nf < 4; ++nf)
            b[nf] = *(const bh8*)&Bsrc[wc * 64 + nf * 16 + li][g * 8];
#pragma unroll
        for (int mf = 0; mf < 4; ++mf)
#pragma unroll
            for (int nf = 0; nf < 4; ++nf)
                acc[mf][nf] = __builtin_amdgcn_mfma_f32_16x16x32_bf16(
                    a[mf], b[nf], acc[mf][nf], 0, 0, 0);
    }

    if (ORIENT == 1) {
#pragma unroll
        for (int mf = 0; mf < 4; ++mf) {
            int c = cm0 + wr * 64 + mf * 16 + g * 4;
            float4 bv = *(const float4*)&bias[c];
#pragma unroll
            for (int nf = 0; nf < 4; ++nf) {
                int p = pp0 + wc * 64 + nf * 16 + li;
                us4 o;
                o[0] = f2bf((acc[mf][nf][0] + bv.x) * scale);
                o[1] = f2bf((acc[mf][nf][1] + bv.y) * scale);
                o[2] = f2bf((acc[mf][nf][2] + bv.z) * scale);
                o[3] = f2bf((acc[mf][nf][3] + bv.w) * scale);
                *(us4*)(outb + (size_t)p * CCH + c) = o;
            }
        }
    } else if (ORIENT == 2) {
#pragma unroll
        for (int nf = 0; nf < 4; ++nf) {
            int c = cm0 + wc * 64 + nf * 16 + li;
            float bv = bias[c];
#pragma unroll
            for (int mf = 0; mf < 4; ++mf) {
                int p = pp0 + wr * 64 + mf * 16 + g * 4;
                int n = p / HWP;
                int pl = p - n * HWP;
                us4 o;
                o[0] = f2bf(acc[mf][nf][0] + bv);
                o[1] = f2bf(acc[mf][nf][1] + bv);
                o[2] = f2bf(acc[mf][nf][2] + bv);
                o[3] = f2bf(acc[mf][nf][3] + bv);
                *(us4*)(outb + (size_t)(n * CCH + c) * HWP + pl) = o;
            }
        }
    } else {   // ORIENT 3: fp32 std layout, inverse window gather
#pragma unroll
        for (int nf = 0; nf < 4; ++nf) {
            int c = cm0 + wc * 64 + nf * 16 + li;
            float bv = bias[c];
#pragma unroll
            for (int mf = 0; mf < 4; ++mf) {
                int p = pp0 + wr * 64 + mf * 16 + g * 4;
                int n = p / HWP;
                int rem = p - n * HWP;
                int win = rem >> 6, t = rem & 63;
                int h = (win / NWIN) * 8 + (t >> 3);
                int w = (win % NWIN) * 8 + (t & 7);
                float4 o;
                o.x = acc[mf][nf][0] + bv;
                o.y = acc[mf][nf][1] + bv;
                o.z = acc[mf][nf][2] + bv;
                o.w = acc[mf][nf][3] + bv;
                *(float4*)(outf + (size_t)(n * CCH + c) * HWP + h * WWD + w) = o;
            }
        }
    }
}

// ---------------------------------------------------------------------------
// MFMA window attention. block = one window (64 tokens); 4 waves x 3 heads.
// q,k: bf16 [p_wg][384]; v: bf16 [n][c][p_local] (= V^T); out: bf16 [p_wg][384].
// ---------------------------------------------------------------------------
__global__ __launch_bounds__(256) void attn(
    const unsigned short* __restrict__ q, const unsigned short* __restrict__ k,
    const unsigned short* __restrict__ v, const float* __restrict__ rpb,
    unsigned short* __restrict__ o)
{
    __shared__ float rpbs[225 * HEADS];
    __shared__ unsigned short Pl[4][64][72];

    int tid = threadIdx.x, lid = tid & 63, wid = tid >> 6;
    int wl = blockIdx.x;
    int n = wl / WINS, winl = wl - n * WINS;
    int li = lid & 15, g = lid >> 4;

    for (int i = tid; i < 225 * HEADS; i += 256) rpbs[i] = rpb[i];
    __syncthreads();

    const fx4 z = (fx4){0.f, 0.f, 0.f, 0.f};

    for (int hq = wid; hq < HEADS; hq += 4) {
        const unsigned short* qp = q + (size_t)(wl * 64) * CCH + hq * HD + g * 8;
        const unsigned short* kp = k + (size_t)(wl * 64) * CCH + hq * HD + g * 8;
        bh8 aq[4], bk[4];
#pragma unroll
        for (int mf = 0; mf < 4; ++mf)
            aq[mf] = *(const bh8*)(qp + (size_t)(mf * 16 + li) * CCH);
#pragma unroll
        for (int nf = 0; nf < 4; ++nf)
            bk[nf] = *(const bh8*)(kp + (size_t)(nf * 16 + li) * CCH);

        fx4 s[4][4];
#pragma unroll
        for (int mf = 0; mf < 4; ++mf)
#pragma unroll
            for (int nf = 0; nf < 4; ++nf)
                s[mf][nf] = __builtin_amdgcn_mfma_f32_16x16x32_bf16(aq[mf], bk[nf], z, 0, 0, 0);

        // relative position bias (analytic index)
#pragma unroll
        for (int mf = 0; mf < 4; ++mf)
#pragma unroll
            for (int nf = 0; nf < 4; ++nf)
#pragma unroll
                for (int r = 0; r < 4; ++r) {
                    int tq = mf * 16 + g * 4 + r, tk = nf * 16 + li;
                    int dy = (tq >> 3) - (tk >> 3) + 7;
                    int dx = (tq & 7) - (tk & 7) + 7;
                    s[mf][nf][r] += rpbs[(dy * 15 + dx) * HEADS + hq];
                }

        // softmax across tk (lane group of 16 shares a row set)
        float inv_[4][4];
#pragma unroll
        for (int mf = 0; mf < 4; ++mf)
#pragma unroll
            for (int r = 0; r < 4; ++r) {
                float m = s[mf][0][r];
#pragma unroll
                for (int nf = 1; nf < 4; ++nf) m = fmaxf(m, s[mf][nf][r]);
                m = fmaxf(m, __shfl_xor(m, 1));
                m = fmaxf(m, __shfl_xor(m, 2));
                m = fmaxf(m, __shfl_xor(m, 4));
                m = fmaxf(m, __shfl_xor(m, 8));
                float sum = 0.f;
#pragma unroll
                for (int nf = 0; nf < 4; ++nf) {
                    float e = __expf(s[mf][nf][r] - m);
                    s[mf][nf][r] = e;
                    sum += e;
                }
                sum += __shfl_xor(sum, 1);
                sum += __shfl_xor(sum, 2);
                sum += __shfl_xor(sum, 4);
                sum += __shfl_xor(sum, 8);
                inv_[mf][r] = 1.f / sum;
            }

        // P -> per-wave LDS, bf16, row-major [tq][tk]
#pragma unroll
        for (int mf = 0; mf < 4; ++mf)
#pragma unroll
            for (int nf = 0; nf < 4; ++nf)
#pragma unroll
                for (int r = 0; r < 4; ++r)
                    Pl[wid][mf * 16 + g * 4 + r][nf * 16 + li] =
                        f2bf(s[mf][nf][r] * inv_[mf][r]);

        // O^T = V^T x P^T : D[d][tq]
        fx4 o2[2][4];
#pragma unroll
        for (int m2 = 0; m2 < 2; ++m2)
#pragma unroll
            for (int nf = 0; nf < 4; ++nf) o2[m2][nf] = z;
#pragma unroll
        for (int ks = 0; ks < 2; ++ks) {
            bh8 av[2], bp[4];
#pragma unroll
            for (int m2 = 0; m2 < 2; ++m2)
                av[m2] = *(const bh8*)(v + (size_t)(n * CCH + hq * HD + m2 * 16 + li) * HWP
                                         + winl * 64 + ks * 32 + g * 8);
#pragma unroll
            for (int nf = 0; nf < 4; ++nf)
                bp[nf] = *(const bh8*)&Pl[wid][nf * 16 + li][ks * 32 + g * 8];
#pragma unroll
            for (int m2 = 0; m2 < 2; ++m2)
#pragma unroll
                for (int nf = 0; nf < 4; ++nf)
                    o2[m2][nf] = __builtin_amdgcn_mfma_f32_16x16x32_bf16(
                        av[m2], bp[nf], o2[m2][nf], 0, 0, 0);
        }
#pragma unroll
        for (int nf = 0; nf < 4; ++nf) {
            int tq = nf * 16 + li;
#pragma unroll
            for (int m2 = 0; m2 < 2; ++m2) {
                int d = hq * HD + m2 * 16 + g * 4;
                us4 ov;
                ov[0] = f2bf(o2[m2][nf][0]);
                ov[1] = f2bf(o2[m2][nf][1]);
                ov[2] = f2bf(o2[m2][nf][2]);
                ov[3] = f2bf(o2[m2][nf][3]);
                *(us4*)(o + (size_t)(wl * 64 + tq) * CCH + d) = ov;
            }
        }
    }
}

// ---------------------------------------------------------------------------
extern "C" void kernel_launch(void* const* d_in, const int* in_sizes, int n_in,
                              void* d_out, int out_size, void* d_ws, size_t ws_size,
                              hipStream_t stream) {
    const float* vid  = (const float*)d_in[0];
    const float* qd_w = (const float*)d_in[1];
    const float* qd_b = (const float*)d_in[2];
    const float* qp_w = (const float*)d_in[3];
    const float* qp_b = (const float*)d_in[4];
    const float* kd_w = (const float*)d_in[5];
    const float* kd_b = (const float*)d_in[6];
    const float* kp_w = (const float*)d_in[7];
    const float* kp_b = (const float*)d_in[8];
    const float* vd_w = (const float*)d_in[9];
    const float* vd_b = (const float*)d_in[10];
    const float* vp_w = (const float*)d_in[11];
    const float* vp_b = (const float*)d_in[12];
    const float* rpb  = (const float*)d_in[13];
    const float* pj_w = (const float*)d_in[14];
    const float* pj_b = (const float*)d_in[15];

    unsigned short* ws16 = (unsigned short*)d_ws;
    unsigned short* tr0 = ws16 + 3 * EELEM;     // [p_wg][c] bf16 (q,k,v pre-GEMM)
    unsigned short* tr1 = ws16 + 4 * EELEM;
    unsigned short* tr2 = ws16 + 5 * EELEM;
    unsigned short* Wb  = ws16 + 6 * EELEM;     // 4 x 147456 bf16
    unsigned short* qb  = ws16;                 // post-GEMM q,k,v
    unsigned short* kb  = ws16 + EELEM;
    unsigned short* vb  = ws16 + 2 * EELEM;
    unsigned short* ob  = tr0;                  // attn out reuses tr region

    wcvt<<<288, 256, 0, stream>>>(qp_w, kp_w, vp_w, pj_w, Wb);
    dwgather<<<NIMG * WINS, 256, 0, stream>>>(
        vid, qd_w, qd_b, kd_w, kd_b, vd_w, vd_b, tr0, tr1, tr2);

    dim3 gg(PTOT / 128, 3);
    const float scale = 0.17677669529663687f;   // 32^-0.5 folded into q
    pw_gemm<1><<<gg, 256, 0, stream>>>(tr0, Wb,             qp_b, scale, qb, nullptr);
    pw_gemm<1><<<gg, 256, 0, stream>>>(tr1, Wb + WMAT,      kp_b, 1.0f,  kb, nullptr);
    pw_gemm<2><<<gg, 256, 0, stream>>>(tr2, Wb + 2 * WMAT,  vp_b, 1.0f,  vb, nullptr);

    attn<<<NIMG * WINS, 256, 0, stream>>>(qb, kb, vb, rpb, ob);

    pw_gemm<3><<<gg, 256, 0, stream>>>(ob, Wb + 3 * WMAT, pj_b, 1.0f, nullptr, (float*)d_out);
}

// Round 5
// 405.424 us; speedup vs baseline: 1.2799x; 1.2799x over previous
//
#include <hip/hip_runtime.h>

#define CCH 384
#define HH 192
#define WWD 192
#define NIMG 2
#define HWP (HH * WWD)        // 36864 pixels per image
#define PTOT (NIMG * HWP)     // 73728
#define HEADS 12
#define HD 32
#define NWIN 24
#define WINS 576              // windows per image
#define EELEM ((size_t)NIMG * CCH * HWP)   // elems per tensor (28,311,552)
#define WMAT 147456           // 384*384

typedef __attribute__((ext_vector_type(8))) short bh8;            // 8 bf16 (MFMA frag)
typedef __attribute__((ext_vector_type(8))) unsigned short us8;
typedef __attribute__((ext_vector_type(4))) unsigned short us4;
typedef __attribute__((ext_vector_type(4))) float fx4;

__device__ __forceinline__ unsigned short f2bf(float f) {
    unsigned u = __float_as_uint(f);
    u += 0x7fffu + ((u >> 16) & 1u);      // round-to-nearest-even
    return (unsigned short)(u >> 16);
}

// ---------------------------------------------------------------------------
// weights fp32 -> bf16 (qp_w, kp_w, vp_w, proj_w concatenated)
// ---------------------------------------------------------------------------
__global__ __launch_bounds__(256) void wcvt(
    const float* __restrict__ a, const float* __restrict__ b,
    const float* __restrict__ c, const float* __restrict__ d,
    unsigned short* __restrict__ o)
{
    int idx8 = (blockIdx.x * 256 + threadIdx.x) * 8;   // 288 blocks * 256 * 8 = 589824 exact
    int which = idx8 / WMAT;
    int loc = idx8 - which * WMAT;
    const float* s = (which == 0) ? a : (which == 1) ? b : (which == 2) ? c : d;
    float4 v0 = *(const float4*)(s + loc);
    float4 v1 = *(const float4*)(s + loc + 4);
    us8 ov;
    ov[0] = f2bf(v0.x); ov[1] = f2bf(v0.y); ov[2] = f2bf(v0.z); ov[3] = f2bf(v0.w);
    ov[4] = f2bf(v1.x); ov[5] = f2bf(v1.y); ov[6] = f2bf(v1.z); ov[7] = f2bf(v1.w);
    *(us8*)(o + idx8) = ov;
}

// ---------------------------------------------------------------------------
// FUSED depthwise 3x3 + bias + window-gather transpose (v3).
// Block = ONE window (8x8) x 64 channels; grid = 1152 windows x 6 ch-chunks
//       = 6912 blocks, XCD-chunked swizzle (strips of 24 windows per XCD).
// Lane = channel (vector weight loads, 128B-contiguous bf16 stores).
// LDS halo: [64 ch][10 rows][12 cols] f32, channel stride 121 (odd ->
// conflict-free reads); 30.3 KB -> 5 blocks/CU.
// ---------------------------------------------------------------------------
__global__ __launch_bounds__(256) void dwgather(
    const float* __restrict__ x,
    const float* __restrict__ qw, const float* __restrict__ qb,
    const float* __restrict__ kw, const float* __restrict__ kb,
    const float* __restrict__ vw, const float* __restrict__ vb,
    unsigned short* __restrict__ oq, unsigned short* __restrict__ ok,
    unsigned short* __restrict__ ov)
{
    __shared__ float halo[64 * 121];        // 30.25 KB

    // bijective XCD swizzle: 6912 = 8 * 864
    int bid = blockIdx.x;
    int b = (bid & 7) * 864 + (bid >> 3);
    // b = ((n*24 + wy)*6 + chv)*24 + wtx  (consecutive b: same strip, same XCD)
    int wtx  = b % 24;
    int strip = b / 24;                     // 0..287
    int chv  = strip % 6;
    int nwy  = strip / 6;                   // 0..47
    int wy   = nwy % 24;
    int n    = nwy / 24;

    int h0 = wy * 8, w0 = wtx * 8;
    int tid = threadIdx.x;
    int c   = tid & 63;                     // channel within chunk (lane-varying)
    int pxg = tid >> 6;                     // wave id: owns pixels pxg*16..+15
    int cg  = chv * 64 + c;
    int widx = n * WINS + wy * NWIN + wtx;

    const float* xbase = x + (size_t)n * CCH * HWP + (size_t)(chv * 64) * HWP;

    // ---- stage halo: 64ch x 10 rows x 12 cols (cols w0-2 .. w0+9) ----
    for (int j = tid; j < 1920; j += 256) {
        int seg = j % 3;
        int t   = j / 3;
        int rr  = t % 10;
        int cc  = t / 10;
        int hr  = h0 - 1 + rr;
        int cb  = w0 - 2 + seg * 4;
        float4 val = make_float4(0.f, 0.f, 0.f, 0.f);
        if (hr >= 0 && hr < HH) {
            const float* p = xbase + (size_t)cc * HWP + (size_t)hr * WWD;
            if (cb >= 0 && cb + 4 <= WWD) {
                val = *(const float4*)(p + cb);
            } else {
                if (cb + 0 >= 0 && cb + 0 < WWD) val.x = p[cb + 0];
                if (cb + 1 >= 0 && cb + 1 < WWD) val.y = p[cb + 1];
                if (cb + 2 >= 0 && cb + 2 < WWD) val.z = p[cb + 2];
                if (cb + 3 >= 0 && cb + 3 < WWD) val.w = p[cb + 3];
            }
        }
        int hb = cc * 121 + rr * 12 + seg * 4;
        halo[hb + 0] = val.x;
        halo[hb + 1] = val.y;
        halo[hb + 2] = val.z;
        halo[hb + 3] = val.w;
    }

    // ---- per-lane weights (vector loads, latency-hidden) ----
    float wq[9], wk[9], wv[9];
#pragma unroll
    for (int t = 0; t < 9; ++t) {
        wq[t] = qw[cg * 9 + t];
        wk[t] = kw[cg * 9 + t];
        wv[t] = vw[cg * 9 + t];
    }
    float bqv = qb[cg], bkv = kb[cg], bvv = vb[cg];

    __syncthreads();

    // ---- compute 16 pixels, store 128B-contiguous (64 lanes = 64 channels) --
#pragma unroll
    for (int i = 0; i < 16; ++i) {
        int px = pxg * 16 + i;
        int pr = px >> 3, pc = px & 7;
        float sq = 0.f, sk = 0.f, sv = 0.f;
#pragma unroll
        for (int dr = 0; dr < 3; ++dr)
#pragma unroll
            for (int dc = 0; dc < 3; ++dc) {
                float xv = halo[c * 121 + (pr + dr) * 12 + pc + dc + 1];
                int t = dr * 3 + dc;
                sq = fmaf(xv, wq[t], sq);
                sk = fmaf(xv, wk[t], sk);
                sv = fmaf(xv, wv[t], sv);
            }
        size_t ob = ((size_t)widx * 64 + px) * CCH + cg;
        oq[ob] = f2bf(sq + bqv);
        ok[ob] = f2bf(sk + bkv);
        ov[ob] = f2bf(sv + bvv);
    }
}

// ---------------------------------------------------------------------------
// bf16 MFMA GEMM over channels. Y: bf16 [p_wg][384] (k contiguous).
// W: bf16 [c_out][384]. 128x128 tile, BK=32, 4 waves, 4x4 16x16 frags/wave.
// ORIENT 1: D[c][p] -> out bf16 [p][c], (acc+bias)*scale      (q, k)
// ORIENT 2: D[p][c] -> out bf16 [n][c][p_local], acc+bias     (v, transposed for attn)
// ORIENT 3: D[p][c] -> out fp32 standard [n][c][h][w], un-gather windows (proj)
// ---------------------------------------------------------------------------
template<int ORIENT>
__global__ __launch_bounds__(256) void pw_gemm(
    const unsigned short* __restrict__ Y, const unsigned short* __restrict__ Wb,
    const float* __restrict__ bias, float scale,
    unsigned short* __restrict__ outb, float* __restrict__ outf)
{
    __shared__ unsigned short Wt[128][40];   // [c_out rows][k], padded
    __shared__ unsigned short Yt[128][40];   // [p rows][k], padded

    int tid = threadIdx.x;
    int pp0 = blockIdx.x * 128;
    int cm0 = blockIdx.y * 128;
    int lid = tid & 63, wid = tid >> 6;
    int wr = wid >> 1, wc = wid & 1;
    int li = lid & 15, g = lid >> 4;
    int srow = tid >> 2;                 // 0..63
    int skoff = (tid & 3) * 8;           // 0,8,16,24

    fx4 acc[4][4];
#pragma unroll
    for (int i = 0; i < 4; ++i)
#pragma unroll
        for (int j = 0; j < 4; ++j) acc[i][j] = (fx4){0.f, 0.f, 0.f, 0.f};

    const unsigned short* WpG = Wb + (size_t)(cm0 + srow) * CCH + skoff;
    const unsigned short* YpG = Y  + (size_t)(pp0 + srow) * CCH + skoff;
    bh8 w0 = *(const bh8*)(WpG);
    bh8 w1 = *(const bh8*)(WpG + (size_t)64 * CCH);
    bh8 y0 = *(const bh8*)(YpG);
    bh8 y1 = *(const bh8*)(YpG + (size_t)64 * CCH);

    typedef unsigned short (*tile_t)[40];
    tile_t Asrc = (ORIENT == 1) ? Wt : Yt;
    tile_t Bsrc = (ORIENT == 1) ? Yt : Wt;

    for (int kt = 0; kt < 12; ++kt) {
        __syncthreads();
        *(bh8*)&Wt[srow][skoff]      = w0;
        *(bh8*)&Wt[64 + srow][skoff] = w1;
        *(bh8*)&Yt[srow][skoff]      = y0;
        *(bh8*)&Yt[64 + srow][skoff] = y1;
        __syncthreads();
        if (kt < 11) {
            int ko = (kt + 1) * 32;
            w0 = *(const bh8*)(WpG + ko);
            w1 = *(const bh8*)(WpG + ko + (size_t)64 * CCH);
            y0 = *(const bh8*)(YpG + ko);
            y1 = *(const bh8*)(YpG + ko + (size_t)64 * CCH);
        }
        bh8 a[4], b[4];
#pragma unroll
        for (int mf = 0; mf < 4; ++mf)
            a[mf] = *(const bh8*)&Asrc[wr * 64 + mf * 16 + li][g * 8];
#pragma unroll
        for (int nf = 0; nf < 4; ++nf)
            b[nf] = *(const bh8*)&Bsrc[wc * 64 + nf * 16 + li][g * 8];
#pragma unroll
        for (int mf = 0; mf < 4; ++mf)
#pragma unroll
            for (int nf = 0; nf < 4; ++nf)
                acc[mf][nf] = __builtin_amdgcn_mfma_f32_16x16x32_bf16(
                    a[mf], b[nf], acc[mf][nf], 0, 0, 0);
    }

    if (ORIENT == 1) {
#pragma unroll
        for (int mf = 0; mf < 4; ++mf) {
            int c = cm0 + wr * 64 + mf * 16 + g * 4;
            float4 bv = *(const float4*)&bias[c];
#pragma unroll
            for (int nf = 0; nf < 4; ++nf) {
                int p = pp0 + wc * 64 + nf * 16 + li;
                us4 o;
                o[0] = f2bf((acc[mf][nf][0] + bv.x) * scale);
                o[1] = f2bf((acc[mf][nf][1] + bv.y) * scale);
                o[2] = f2bf((acc[mf][nf][2] + bv.z) * scale);
                o[3] = f2bf((acc[mf][nf][3] + bv.w) * scale);
                *(us4*)(outb + (size_t)p * CCH + c) = o;
            }
        }
    } else if (ORIENT == 2) {
#pragma unroll
        for (int nf = 0; nf < 4; ++nf) {
            int c = cm0 + wc * 64 + nf * 16 + li;
            float bv = bias[c];
#pragma unroll
            for (int mf = 0; mf < 4; ++mf) {
                int p = pp0 + wr * 64 + mf * 16 + g * 4;
                int n = p / HWP;
                int pl = p - n * HWP;
                us4 o;
                o[0] = f2bf(acc[mf][nf][0] + bv);
                o[1] = f2bf(acc[mf][nf][1] + bv);
                o[2] = f2bf(acc[mf][nf][2] + bv);
                o[3] = f2bf(acc[mf][nf][3] + bv);
                *(us4*)(outb + (size_t)(n * CCH + c) * HWP + pl) = o;
            }
        }
    } else {   // ORIENT 3: fp32 std layout, inverse window gather
#pragma unroll
        for (int nf = 0; nf < 4; ++nf) {
            int c = cm0 + wc * 64 + nf * 16 + li;
            float bv = bias[c];
#pragma unroll
            for (int mf = 0; mf < 4; ++mf) {
                int p = pp0 + wr * 64 + mf * 16 + g * 4;
                int n = p / HWP;
                int rem = p - n * HWP;
                int win = rem >> 6, t = rem & 63;
                int h = (win / NWIN) * 8 + (t >> 3);
                int w = (win % NWIN) * 8 + (t & 7);
                float4 o;
                o.x = acc[mf][nf][0] + bv;
                o.y = acc[mf][nf][1] + bv;
                o.z = acc[mf][nf][2] + bv;
                o.w = acc[mf][nf][3] + bv;
                *(float4*)(outf + (size_t)(n * CCH + c) * HWP + h * WWD + w) = o;
            }
        }
    }
}

// ---------------------------------------------------------------------------
// MFMA window attention. block = one window (64 tokens); 4 waves x 3 heads.
// q,k: bf16 [p_wg][384]; v: bf16 [n][c][p_local] (= V^T); out: bf16 [p_wg][384].
// ---------------------------------------------------------------------------
__global__ __launch_bounds__(256) void attn(
    const unsigned short* __restrict__ q, const unsigned short* __restrict__ k,
    const unsigned short* __restrict__ v, const float* __restrict__ rpb,
    unsigned short* __restrict__ o)
{
    __shared__ float rpbs[225 * HEADS];
    __shared__ unsigned short Pl[4][64][72];

    int tid = threadIdx.x, lid = tid & 63, wid = tid >> 6;
    int wl = blockIdx.x;
    int n = wl / WINS, winl = wl - n * WINS;
    int li = lid & 15, g = lid >> 4;

    for (int i = tid; i < 225 * HEADS; i += 256) rpbs[i] = rpb[i];
    __syncthreads();

    const fx4 z = (fx4){0.f, 0.f, 0.f, 0.f};

    for (int hq = wid; hq < HEADS; hq += 4) {
        const unsigned short* qp = q + (size_t)(wl * 64) * CCH + hq * HD + g * 8;
        const unsigned short* kp = k + (size_t)(wl * 64) * CCH + hq * HD + g * 8;
        bh8 aq[4], bk[4];
#pragma unroll
        for (int mf = 0; mf < 4; ++mf)
            aq[mf] = *(const bh8*)(qp + (size_t)(mf * 16 + li) * CCH);
#pragma unroll
        for (int nf = 0; nf < 4; ++nf)
            bk[nf] = *(const bh8*)(kp + (size_t)(nf * 16 + li) * CCH);

        fx4 s[4][4];
#pragma unroll
        for (int mf = 0; mf < 4; ++mf)
#pragma unroll
            for (int nf = 0; nf < 4; ++nf)
                s[mf][nf] = __builtin_amdgcn_mfma_f32_16x16x32_bf16(aq[mf], bk[nf], z, 0, 0, 0);

        // relative position bias (analytic index)
#pragma unroll
        for (int mf = 0; mf < 4; ++mf)
#pragma unroll
            for (int nf = 0; nf < 4; ++nf)
#pragma unroll
                for (int r = 0; r < 4; ++r) {
                    int tq = mf * 16 + g * 4 + r, tk = nf * 16 + li;
                    int dy = (tq >> 3) - (tk >> 3) + 7;
                    int dx = (tq & 7) - (tk & 7) + 7;
                    s[mf][nf][r] += rpbs[(dy * 15 + dx) * HEADS + hq];
                }

        // softmax across tk (lane group of 16 shares a row set)
        float inv_[4][4];
#pragma unroll
        for (int mf = 0; mf < 4; ++mf)
#pragma unroll
            for (int r = 0; r < 4; ++r) {
                float m = s[mf][0][r];
#pragma unroll
                for (int nf = 1; nf < 4; ++nf) m = fmaxf(m, s[mf][nf][r]);
                m = fmaxf(m, __shfl_xor(m, 1));
                m = fmaxf(m, __shfl_xor(m, 2));
                m = fmaxf(m, __shfl_xor(m, 4));
                m = fmaxf(m, __shfl_xor(m, 8));
                float sum = 0.f;
#pragma unroll
                for (int nf = 0; nf < 4; ++nf) {
                    float e = __expf(s[mf][nf][r] - m);
                    s[mf][nf][r] = e;
                    sum += e;
                }
                sum += __shfl_xor(sum, 1);
                sum += __shfl_xor(sum, 2);
                sum += __shfl_xor(sum, 4);
                sum += __shfl_xor(sum, 8);
                inv_[mf][r] = 1.f / sum;
            }

        // P -> per-wave LDS, bf16, row-major [tq][tk]
#pragma unroll
        for (int mf = 0; mf < 4; ++mf)
#pragma unroll
            for (int nf = 0; nf < 4; ++nf)
#pragma unroll
                for (int r = 0; r < 4; ++r)
                    Pl[wid][mf * 16 + g * 4 + r][nf * 16 + li] =
                        f2bf(s[mf][nf][r] * inv_[mf][r]);

        // O^T = V^T x P^T : D[d][tq]
        fx4 o2[2][4];
#pragma unroll
        for (int m2 = 0; m2 < 2; ++m2)
#pragma unroll
            for (int nf = 0; nf < 4; ++nf) o2[m2][nf] = z;
#pragma unroll
        for (int ks = 0; ks < 2; ++ks) {
            bh8 av[2], bp[4];
#pragma unroll
            for (int m2 = 0; m2 < 2; ++m2)
                av[m2] = *(const bh8*)(v + (size_t)(n * CCH + hq * HD + m2 * 16 + li) * HWP
                                         + winl * 64 + ks * 32 + g * 8);
#pragma unroll
            for (int nf = 0; nf < 4; ++nf)
                bp[nf] = *(const bh8*)&Pl[wid][nf * 16 + li][ks * 32 + g * 8];
#pragma unroll
            for (int m2 = 0; m2 < 2; ++m2)
#pragma unroll
                for (int nf = 0; nf < 4; ++nf)
                    o2[m2][nf] = __builtin_amdgcn_mfma_f32_16x16x32_bf16(
                        av[m2], bp[nf], o2[m2][nf], 0, 0, 0);
        }
#pragma unroll
        for (int nf = 0; nf < 4; ++nf) {
            int tq = nf * 16 + li;
#pragma unroll
            for (int m2 = 0; m2 < 2; ++m2) {
                int d = hq * HD + m2 * 16 + g * 4;
                us4 ov;
                ov[0] = f2bf(o2[m2][nf][0]);
                ov[1] = f2bf(o2[m2][nf][1]);
                ov[2] = f2bf(o2[m2][nf][2]);
                ov[3] = f2bf(o2[m2][nf][3]);
                *(us4*)(o + (size_t)(wl * 64 + tq) * CCH + d) = ov;
            }
        }
    }
}

// ---------------------------------------------------------------------------
extern "C" void kernel_launch(void* const* d_in, const int* in_sizes, int n_in,
                              void* d_out, int out_size, void* d_ws, size_t ws_size,
                              hipStream_t stream) {
    const float* vid  = (const float*)d_in[0];
    const float* qd_w = (const float*)d_in[1];
    const float* qd_b = (const float*)d_in[2];
    const float* qp_w = (const float*)d_in[3];
    const float* qp_b = (const float*)d_in[4];
    const float* kd_w = (const float*)d_in[5];
    const float* kd_b = (const float*)d_in[6];
    const float* kp_w = (const float*)d_in[7];
    const float* kp_b = (const float*)d_in[8];
    const float* vd_w = (const float*)d_in[9];
    const float* vd_b = (const float*)d_in[10];
    const float* vp_w = (const float*)d_in[11];
    const float* vp_b = (const float*)d_in[12];
    const float* rpb  = (const float*)d_in[13];
    const float* pj_w = (const float*)d_in[14];
    const float* pj_b = (const float*)d_in[15];

    unsigned short* ws16 = (unsigned short*)d_ws;
    unsigned short* tr0 = ws16 + 3 * EELEM;     // [p_wg][c] bf16 (q,k,v pre-GEMM)
    unsigned short* tr1 = ws16 + 4 * EELEM;
    unsigned short* tr2 = ws16 + 5 * EELEM;
    unsigned short* Wb  = ws16 + 6 * EELEM;     // 4 x 147456 bf16
    unsigned short* qb  = ws16;                 // post-GEMM q,k,v
    unsigned short* kb  = ws16 + EELEM;
    unsigned short* vb  = ws16 + 2 * EELEM;
    unsigned short* ob  = tr0;                  // attn out reuses tr region

    wcvt<<<288, 256, 0, stream>>>(qp_w, kp_w, vp_w, pj_w, Wb);
    dwgather<<<NIMG * WINS * 6, 256, 0, stream>>>(
        vid, qd_w, qd_b, kd_w, kd_b, vd_w, vd_b, tr0, tr1, tr2);

    dim3 gg(PTOT / 128, 3);
    const float scale = 0.17677669529663687f;   // 32^-0.5 folded into q
    pw_gemm<1><<<gg, 256, 0, stream>>>(tr0, Wb,             qp_b, scale, qb, nullptr);
    pw_gemm<1><<<gg, 256, 0, stream>>>(tr1, Wb + WMAT,      kp_b, 1.0f,  kb, nullptr);
    pw_gemm<2><<<gg, 256, 0, stream>>>(tr2, Wb + 2 * WMAT,  vp_b, 1.0f,  vb, nullptr);

    attn<<<NIMG * WINS, 256, 0, stream>>>(qb, kb, vb, rpb, ob);

    pw_gemm<3><<<gg, 256, 0, stream>>>(ob, Wb + 3 * WMAT, pj_b, 1.0f, nullptr, (float*)d_out);
}